// Round 13
// baseline (1765.346 us; speedup 1.0000x reference)
//
#include <hip/hip_runtime.h>

// Fused persistent stacked-GRU kernel for MI355X (gfx950).
// Round-13: ONE 1024-thread workgroup per CU = TWO independent 8-wave groups,
// each running the R12 3-stage pipeline (p||gate||main, mirrored A-rows,
// persistent-Z) on 4 batch rows. Same-role waves of the two groups share a
// SIMD -> latency overlap without inter-workgroup scheduling.
// __launch_bounds__(1024,1): 2nd arg is min BLOCKS/CU (CUDA semantics --
// (512,4)/(1024,4) produced the 64-VGPR spills of R2/R5/R6). Cap 128, need ~104.
// LDS tiles shrunk to 8 rows (PX=512; rows 8-15 were never touched since
// mirroring) -> 2 groups = 36,864 B total. Mirror row = lane&3 (4 real rows).

#define T_STEPS 512
#define B_BATCH 2048
#define D_IN    132
#define NROWS_G 4              // rows per group; block covers 8
#define NBLOCKS 256
#define STEP2   (B_BATCH * D_IN / 2)   // f32x2 per timestep
#define NITEMS  (NROWS_G * 66)         // 264 f32x2 per step per group

typedef _Float16 f16x8 __attribute__((ext_vector_type(8)));
typedef float    f32x4 __attribute__((ext_vector_type(4)));
typedef float    f32x2 __attribute__((ext_vector_type(2)));

#define MFMA16(a, b, c) __builtin_amdgcn_mfma_f32_16x16x32_f16((a), (b), (c), 0, 0, 0)

// Per-group LDS tiles [8 rows][64 cols] fp16 = 512 elems each; PX = slot stride.
#define PX    512
#define AP1   0      // x_p1 cols 0..48                  (2 slots)
#define AP2   1024   // x_p2 cols 0..48                  (2 slots)
#define AG    2048   // h1:0-19 h2:20-39 xg:40-47        (4 slots)
#define AR    4096   // gate:0-15 xr:16-41               (4 slots)
#define AP1H  6144   // h1 cols 0..19                    (2 slots)
#define AP2H  7168   // h2 cols 0..19                    (2 slots)
#define AH    8192   // h cols 0..63                     (2 slots)
#define GRP_N 9216
#define LDS_N 18432

// Raw barrier: LDS visibility only (lgkmcnt), NO vmcnt drain -> HBM prefetch
// stays in flight across barriers. seq read-only, out write-only.
#define BARRIER() do { \
    asm volatile("s_waitcnt lgkmcnt(0)\n\ts_barrier" ::: "memory"); \
    __builtin_amdgcn_sched_barrier(0); \
  } while (0)

__device__ __forceinline__ int swz(int row, int col) {
  return row * 64 + (((col >> 3) ^ (row & 7)) << 3) + (col & 7);
}

// A-fragment read with MIRRORED rows: row = lane&3 (rows 4-15 duplicate 0-3).
__device__ __forceinline__ f16x8 ldsFrag(const _Float16* L, int base, int lane, int kt) {
  int row = lane & 3;
  int blk = ((kt << 2) + (lane >> 4)) ^ row;
  return *reinterpret_cast<const f16x8*>(L + base + row * 64 + blk * 8);
}

__device__ __forceinline__ f16x8 mkfrag(const float* W, int row, int K, int kbase, int lane, bool ok) {
  f16x8 f;
  int k0 = kbase + ((lane >> 4) << 3);
#pragma unroll
  for (int j = 0; j < 8; ++j) {
    int k = k0 + j;
    float v = 0.0f;
    if (ok && k < K) v = W[row * K + k];
    f[j] = (_Float16)v;
  }
  return f;
}

__device__ __forceinline__ float rcpf(float x) { return __builtin_amdgcn_rcpf(x); }
__device__ __forceinline__ float ex2(float x)  { return __builtin_amdgcn_exp2f(x); }

__global__ __launch_bounds__(1024, 1) void rnn_fused(
    const float* __restrict__ seq,
    const float* __restrict__ p1Wih, const float* __restrict__ p1Whh,
    const float* __restrict__ p1bih, const float* __restrict__ p1bhh,
    const float* __restrict__ p2Wih, const float* __restrict__ p2Whh,
    const float* __restrict__ p2bih, const float* __restrict__ p2bhh,
    const float* __restrict__ gW,    const float* __restrict__ gb,
    const float* __restrict__ rWih,  const float* __restrict__ rWhh,
    const float* __restrict__ rbih,  const float* __restrict__ rbhh,
    float* __restrict__ out)
{
  __shared__ __align__(16) _Float16 lds[LDS_N];
  const int tid  = threadIdx.x;
  const int lane = tid & 63;
  const int wv   = tid >> 6;          // 0..15
  const int grp  = wv >> 3;           // 0,1
  const int w8   = wv & 7;            // wave within group
  const bool isR = (w8 < 4);
  _Float16* L    = lds + grp * GRP_N;
  const int b0   = blockIdx.x * 8 + grp * NROWS_G;
  const int ul   = lane & 15;
  const bool lo  = (lane < 32);
  // 4 real rows: lanes with ((lane>>4)&1)==0 are writers; lo lanes own rows
  // {0,1}, hi lanes rows {2,3}. Other lanes compute duplicates, write nothing.
  const bool writer = (((lane >> 4) & 1) == 0);
  const int row0 = lo ? 0 : 2;
  const float C1 = 1.44269504089f;

  for (int i = tid; i < LDS_N; i += 1024) lds[i] = (_Float16)0.0f;

  // ---------------- r-wave state (staging + main GRU) ----------------
  f16x8 fghr[2], fghz[2], fghn[2], fgir[2], fgiz[2], fgin[2];
  float nbr2 = 0, nbz2 = 0, bin2 = 0, bhn2 = 0;
  float hq2[2] = {0, 0};
  int stAddr[2][2]; int ldIdx[2] = {0, 0};
  bool stOK[2] = {false, false}, isP[2] = {false, false};
  int ahw2[2] = {0, 0};
  float* outp = nullptr;

  // ---------------- p-wave state (p-GRUs + gate) ----------------
  f16x8 pgi0[2], pgi1[2], pgi2[2], pgh0, pgh1, pgh2, fgw[2];
  float nbr = 0, nbz = 0, bin = 0, bhn = 0, gbias = 0;
  float h1q2[2] = {0, 0};
  int apB = 0, aphB = 0, up = 0; bool uok = false;
  int agw2[2] = {0, 0}, aphw2[2] = {0, 0}, arw2[2] = {0, 0};

  if (isR) {
    const int uR = w8 * 16 + ul;
    fghr[0] = mkfrag(rWhh,       uR, 64,  0, lane, true);
    fghr[1] = mkfrag(rWhh,       uR, 64, 32, lane, true);
    fghz[0] = mkfrag(rWhh,  64 + uR, 64,  0, lane, true);
    fghz[1] = mkfrag(rWhh,  64 + uR, 64, 32, lane, true);
    fghn[0] = mkfrag(rWhh, 128 + uR, 64,  0, lane, true);
    fghn[1] = mkfrag(rWhh, 128 + uR, 64, 32, lane, true);
    fgir[0] = mkfrag(rWih,       uR, 42,  0, lane, true);
    fgir[1] = mkfrag(rWih,       uR, 42, 32, lane, true);
    fgiz[0] = mkfrag(rWih,  64 + uR, 42,  0, lane, true);
    fgiz[1] = mkfrag(rWih,  64 + uR, 42, 32, lane, true);
    fgin[0] = mkfrag(rWih, 128 + uR, 42,  0, lane, true);
    fgin[1] = mkfrag(rWih, 128 + uR, 42, 32, lane, true);
    nbr2 = -C1 * (rbih[uR] + rbhh[uR]);
    nbz2 = -C1 * (rbih[64 + uR] + rbhh[64 + uR]);
    bin2 = rbih[128 + uR]; bhn2 = rbhh[128 + uR];
    ahw2[0] = AH + swz(row0, uR);
    ahw2[1] = AH + swz(row0 + 1, uR);
    // staging map: 264 f32x2 items over the group's 256 r-threads, 2 slots
#pragma unroll
    for (int it = 0; it < 2; ++it) {
      int ii = it * 256 + (w8 * 64 + lane);
      stOK[it] = (ii < NITEMS);
      int iic = stOK[it] ? ii : (NITEMS - 1);
      ldIdx[it] = iic;
      int rr = iic / 66, c2 = iic % 66;
      isP[it] = (c2 < 49);
#pragma unroll
      for (int e = 0; e < 2; ++e) {
        int c = c2 * 2 + e;
        int tb, col;
        if (c < 49)       { tb = AP1; col = c; }
        else if (c < 98)  { tb = AP2; col = c - 49; }
        else if (c < 106) { tb = AG;  col = 40 + (c - 98); }
        else              { tb = AR;  col = 16 + (c - 106); }
        stAddr[it][e] = tb + swz(rr, col);
      }
    }
    outp = out + (size_t)(b0 + row0) * 64 + uR;
  } else {
    const int pw  = w8 - 4;
    const int gru = pw >> 1;
    const int s   = pw & 1;
    const float* Wih = gru ? p2Wih : p1Wih;
    const float* Whh = gru ? p2Whh : p1Whh;
    const float* bih = gru ? p2bih : p1bih;
    const float* bhh = gru ? p2bhh : p1bhh;
    up  = s * 16 + ul;
    uok = (up < 20);
    pgi0[0] = mkfrag(Wih,      up, 49,  0, lane, uok);
    pgi0[1] = mkfrag(Wih,      up, 49, 32, lane, uok);
    pgh0    = mkfrag(Whh,      up, 20,  0, lane, uok);
    pgi1[0] = mkfrag(Wih, 20 + up, 49,  0, lane, uok);
    pgi1[1] = mkfrag(Wih, 20 + up, 49, 32, lane, uok);
    pgh1    = mkfrag(Whh, 20 + up, 20,  0, lane, uok);
    pgi2[0] = mkfrag(Wih, 40 + up, 49,  0, lane, uok);
    pgi2[1] = mkfrag(Wih, 40 + up, 49, 32, lane, uok);
    pgh2    = mkfrag(Whh, 40 + up, 20,  0, lane, uok);
    fgw[0]  = mkfrag(gW, ul, 48,  0, lane, true);
    fgw[1]  = mkfrag(gW, ul, 48, 32, lane, true);
    gbias = gb[ul];
    if (uok) {
      nbr = -C1 * (bih[up] + bhh[up]);
      nbz = -C1 * (bih[20 + up] + bhh[20 + up]);
      bin = bih[40 + up]; bhn = bhh[40 + up];
    }
    apB  = gru ? AP2  : AP1;
    aphB = gru ? AP2H : AP1H;
    const int gcol = gru ? (20 + up) : up;
#pragma unroll
    for (int j = 0; j < 2; ++j) {
      agw2[j]  = AG + swz(row0 + j, gcol);
      aphw2[j] = aphB + swz(row0 + j, up);
      arw2[j]  = AR + swz(row0 + j, ul);
    }
  }

  __syncthreads();  // zeros visible

  // ---- prologue (r-waves): load x(0..3) into 4 slots; stage x(0) -> slot 0 ----
  f32x2 rs0[2], rs1[2], rs2[2], rs3[2];
  const f32x2* spR = nullptr;
  if (isR) {
    const f32x2* sp = reinterpret_cast<const f32x2*>(seq) + (size_t)b0 * (D_IN / 2);
#pragma unroll
    for (int it = 0; it < 2; ++it) {
      rs0[it] = sp[ldIdx[it]];
      rs1[it] = sp[(size_t)1 * STEP2 + ldIdx[it]];
      rs2[it] = sp[(size_t)2 * STEP2 + ldIdx[it]];
      rs3[it] = sp[(size_t)3 * STEP2 + ldIdx[it]];
    }
#pragma unroll
    for (int it = 0; it < 2; ++it) if (stOK[it]) {
      L[stAddr[it][0]] = (_Float16)rs0[it][0];   // all classes -> slot 0
      L[stAddr[it][1]] = (_Float16)rs0[it][1];
    }
    spR = sp + (size_t)4 * STEP2;
  }
  __syncthreads();

  const f32x4 Z = {0.0f, 0.0f, 0.0f, 0.0f};  // persistent zero C-in

  // ---- r-wave phase f: stage x(f+1), prefetch x(f+4), main(t=f-2) ----
  auto rPhase = [&](int offP, int offGR, int slotA, int ahR, int ahW,
                    bool doMain, bool doStage, f32x2 (&rsStage)[2], f32x2 (&rsLoad)[2],
                    bool advance) {
    // prefetch x(min(f+4,511)); stays in flight past barriers
#pragma unroll
    for (int it = 0; it < 2; ++it) rsLoad[it] = spR[ldIdx[it]];
    if (advance) spR += STEP2;
    if (doStage) {
#pragma unroll
      for (int it = 0; it < 2; ++it) if (stOK[it]) {
        const int off = isP[it] ? offP : offGR;
        L[off + stAddr[it][0]] = (_Float16)rsStage[it][0];
        L[off + stAddr[it][1]] = (_Float16)rsStage[it][1];
      }
    }
    if (doMain) {
      f16x8 r0  = ldsFrag(L, AR + slotA, lane, 0);
      f16x8 r1  = ldsFrag(L, AR + slotA, lane, 1);
      f16x8 h0  = ldsFrag(L, AH + ahR, lane, 0);
      f16x8 h1f = ldsFrag(L, AH + ahR, lane, 1);
      f32x4 cR  = MFMA16(h0, fghr[0], Z);
      f32x4 cZ  = MFMA16(h0, fghz[0], Z);
      f32x4 cHN = MFMA16(h0, fghn[0], Z);
      cR  = MFMA16(h1f, fghr[1], cR);
      cZ  = MFMA16(h1f, fghz[1], cZ);
      cHN = MFMA16(h1f, fghn[1], cHN);
      cR  = MFMA16(r0, fgir[0], cR);  cR  = MFMA16(r1, fgir[1], cR);
      cZ  = MFMA16(r0, fgiz[0], cZ);  cZ  = MFMA16(r1, fgiz[1], cZ);
      f32x4 cIN = MFMA16(r0, fgin[0], Z);
      cIN = MFMA16(r1, fgin[1], cIN);
      // lanes use their OWN q-pair (valid: mirrored A-rows make them real)
      float xRv[2] = { lo ? cR[0]  : cR[2],  lo ? cR[1]  : cR[3]  };
      float xZv[2] = { lo ? cZ[0]  : cZ[2],  lo ? cZ[1]  : cZ[3]  };
      float xHv[2] = { lo ? cHN[0] : cHN[2], lo ? cHN[1] : cHN[3] };
      float xIv[2] = { lo ? cIN[0] : cIN[2], lo ? cIN[1] : cIN[3] };
#pragma unroll
      for (int j = 0; j < 2; ++j) {
        float r   = rcpf(1.0f + ex2(fmaf(xRv[j], -C1, nbr2)));
        float z   = rcpf(1.0f + ex2(fmaf(xZv[j], -C1, nbz2)));
        float pre = fmaf(r, xHv[j] + bhn2, xIv[j] + bin2);
        float e2  = ex2(pre * (2.0f * C1));
        float n   = 1.0f - 2.0f * rcpf(1.0f + e2);
        float hv  = fmaf(z, hq2[j] - n, n);
        hq2[j] = hv;
        if (writer) {
          outp[j * 64] = hv;
          L[ahW + ahw2[j]] = (_Float16)hv;
        }
      }
      outp += (size_t)B_BATCH * 64;
    }
  };

  // ---- p-wave phase f: p-GRUs(t=f) + gate(t=f-1) ----
  auto pPhase = [&](int pj, int agWr, int aphWr, int gSlot, bool doComp, bool doGate) {
    if (doComp) {
      f16x8 a0 = ldsFrag(L, apB + pj, lane, 0);
      f16x8 a1 = ldsFrag(L, apB + pj, lane, 1);
      f16x8 ah = ldsFrag(L, aphB + pj, lane, 0);
      f32x4 aR  = MFMA16(a0, pgi0[0], Z);
      f32x4 aZ  = MFMA16(a0, pgi1[0], Z);
      f32x4 aIN = MFMA16(a0, pgi2[0], Z);
      f32x4 aHN = MFMA16(ah, pgh2, Z);
      aR  = MFMA16(a1, pgi0[1], aR);  aR = MFMA16(ah, pgh0, aR);
      aZ  = MFMA16(a1, pgi1[1], aZ);  aZ = MFMA16(ah, pgh1, aZ);
      aIN = MFMA16(a1, pgi2[1], aIN);
      float xRv[2] = { lo ? aR[0]  : aR[2],  lo ? aR[1]  : aR[3]  };
      float xZv[2] = { lo ? aZ[0]  : aZ[2],  lo ? aZ[1]  : aZ[3]  };
      float xIv[2] = { lo ? aIN[0] : aIN[2], lo ? aIN[1] : aIN[3] };
      float xHv[2] = { lo ? aHN[0] : aHN[2], lo ? aHN[1] : aHN[3] };
#pragma unroll
      for (int j = 0; j < 2; ++j) {
        float r   = rcpf(1.0f + ex2(fmaf(xRv[j], -C1, nbr)));
        float z   = rcpf(1.0f + ex2(fmaf(xZv[j], -C1, nbz)));
        float pre = fmaf(r, xHv[j] + bhn, xIv[j] + bin);
        float e2  = ex2(pre * (2.0f * C1));
        float n   = 1.0f - 2.0f * rcpf(1.0f + e2);
        float hv  = fmaf(z, h1q2[j] - n, n);
        h1q2[j] = hv;
        if (writer && uok) {
          _Float16 hh = (_Float16)hv;
          L[agWr + agw2[j]]  = hh;   // -> AG slot f&3 (gate input, read @f+1)
          L[aphWr + aphw2[j]] = hh;  // -> own h-path, read @f+1
        }
      }
    }
    if (doGate) {
      f16x8 g0 = ldsFrag(L, AG + gSlot, lane, 0);
      f16x8 g1 = ldsFrag(L, AG + gSlot, lane, 1);
      f32x4 cG = MFMA16(g0, fgw[0], Z);
      cG = MFMA16(g1, fgw[1], cG);
      float gv0 = lo ? cG[0] : cG[2], gv1 = lo ? cG[1] : cG[3];
      if (writer) {
        L[gSlot + arw2[0]] = (_Float16)fmaxf(gv0 + gbias, 0.0f);  // AR slot (f-1)&3
        L[gSlot + arw2[1]] = (_Float16)fmaxf(gv1 + gbias, 0.0f);
      }
    }
  };

  // ---- main loop: f = 4i+j, i in [0,127], j in [0,3] (both groups in step) ----
  for (int i = 0; i < T_STEPS / 4; ++i) {
    const bool i0 = (i == 0);
    const int f0 = 4 * i;
    // j=0: offP=PX offGR=PX slotA=2PX ahR=PX ahW=0 | p: pj=0 agWr=0 aphWr=PX gSlot=3PX
    if (isR) rPhase(PX, PX, 2 * PX, PX, 0, !i0, true, rs1, rs0, (f0 + 5 < T_STEPS));
    else     pPhase(0, 0, PX, 3 * PX, true, !i0);
    BARRIER();
    // j=1: offP=0 offGR=2PX slotA=3PX ahR=0 ahW=PX | p: pj=PX agWr=PX aphWr=0 gSlot=0
    if (isR) rPhase(0, 2 * PX, 3 * PX, 0, PX, !i0, true, rs2, rs1, (f0 + 6 < T_STEPS));
    else     pPhase(PX, PX, 0, 0, true, true);
    BARRIER();
    // j=2: offP=PX offGR=3PX slotA=0 ahR=PX ahW=0 | p: pj=0 agWr=2PX aphWr=PX gSlot=PX
    if (isR) rPhase(PX, 3 * PX, 0, PX, 0, true, true, rs3, rs2, (f0 + 7 < T_STEPS));
    else     pPhase(0, 2 * PX, PX, PX, true, true);
    BARRIER();
    // j=3: offP=0 offGR=0 slotA=PX ahR=0 ahW=PX | p: pj=PX agWr=3PX aphWr=0 gSlot=2PX
    if (isR) rPhase(0, 0, PX, 0, PX, true, (i != T_STEPS / 4 - 1), rs0, rs3,
                    (f0 + 8 < T_STEPS));
    else     pPhase(PX, 3 * PX, 0, 2 * PX, true, true);
    BARRIER();
  }
  // ---- epilogue: f=512 (even): main(510) slotA=2PX ahR=PX ahW=0; p: gate(511) ----
  if (isR) rPhase(0, 0, 2 * PX, PX, 0, true, false, rs0, rs1, false);
  else     pPhase(0, 0, PX, 3 * PX, false, true);
  BARRIER();
  // ---- f=513 (odd): main(511) slotA=3PX ahR=0 ahW=PX ----
  if (isR) rPhase(0, 0, 3 * PX, 0, PX, true, false, rs0, rs1, false);
}

extern "C" void kernel_launch(void* const* d_in, const int* in_sizes, int n_in,
                              void* d_out, int out_size, void* d_ws, size_t ws_size,
                              hipStream_t stream) {
  (void)in_sizes; (void)n_in; (void)d_ws; (void)ws_size; (void)out_size;
  const float* seq   = (const float*)d_in[0];
  const float* p1Wih = (const float*)d_in[1];
  const float* p1Whh = (const float*)d_in[2];
  const float* p1bih = (const float*)d_in[3];
  const float* p1bhh = (const float*)d_in[4];
  const float* p2Wih = (const float*)d_in[5];
  const float* p2Whh = (const float*)d_in[6];
  const float* p2bih = (const float*)d_in[7];
  const float* p2bhh = (const float*)d_in[8];
  const float* gW    = (const float*)d_in[9];
  const float* gb    = (const float*)d_in[10];
  const float* rWih  = (const float*)d_in[11];
  const float* rWhh  = (const float*)d_in[12];
  const float* rbih  = (const float*)d_in[13];
  const float* rbhh  = (const float*)d_in[14];
  float* out = (float*)d_out;
  hipLaunchKernelGGL(rnn_fused, dim3(NBLOCKS), dim3(1024), 0, stream,
                     seq, p1Wih, p1Whh, p1bih, p1bhh,
                     p2Wih, p2Whh, p2bih, p2bhh,
                     gW, gb, rWih, rWhh, rbih, rbhh, out);
}

// Round 14
// 352.328 us; speedup vs baseline: 5.0105x; 5.0105x over previous
//
#include <hip/hip_runtime.h>

// Fused persistent stacked-GRU kernel for MI355X (gfx950).
// Round-14: R12 3-stage pipeline (p||gate||main, mirrored A-rows, persistent-Z)
// + DIRECT-GLOBAL x_p A-FRAGMENTS: p-waves load x_p1/x_p2 straight from seq
// into registers (2 x dwordx4 per k-half, 2-phase prefetch) -- A-frag lane
// layout maps to 8 consecutive floats of one row. No masking needed: B-frags
// already zero k>=49. Removes AP1/AP2 tiles, r's P-class staging (2 of 3
// slots), p's 2 leading ds_read_b128. r stages only xg/xr (136 items, 1 slot).
// 256 blocks x 8 rows, launch_bounds(512,2) (the only no-spill config).

#define T_STEPS 512
#define B_BATCH 2048
#define D_IN    132
#define NROWS   8
#define NBLOCKS 256
#define STEP2   (B_BATCH * D_IN / 2)   // f32x2 per timestep
#define STEPF   (B_BATCH * D_IN)       // floats per timestep
#define NGR     (NROWS * 17)           // 136 GR-class f32x2 items per step

typedef _Float16 f16x8 __attribute__((ext_vector_type(8)));
typedef float    f32x4 __attribute__((ext_vector_type(4)));
typedef float    f32x2 __attribute__((ext_vector_type(2)));

#define MFMA16(a, b, c) __builtin_amdgcn_mfma_f32_16x16x32_f16((a), (b), (c), 0, 0, 0)

// LDS tiles [16 rows][64 cols] fp16 = 1024 elems each; PX = slot stride.
#define PX    1024
#define AG    0      // h1:0-19 h2:20-39 xg:40-47        (4 slots)
#define AR    4096   // gate:0-15 xr:16-41               (4 slots)
#define AP1H  8192   // h1 cols 0..19                    (2 slots)
#define AP2H  10240  // h2 cols 0..19                    (2 slots)
#define AH    12288  // h cols 0..63                     (2 slots)
#define LDS_N 14336

// Raw barrier: LDS visibility only (lgkmcnt), NO vmcnt drain -> HBM prefetch
// stays in flight across barriers. seq read-only, out write-only.
#define BARRIER() do { \
    asm volatile("s_waitcnt lgkmcnt(0)\n\ts_barrier" ::: "memory"); \
    __builtin_amdgcn_sched_barrier(0); \
  } while (0)

__device__ __forceinline__ int swz(int row, int col) {
  return row * 64 + (((col >> 3) ^ (row & 7)) << 3) + (col & 7);
}

// A-fragment read with MIRRORED rows: row = lane&7 (rows 8-15 duplicate 0-7).
__device__ __forceinline__ f16x8 ldsFrag(const _Float16* lds, int base, int lane, int kt) {
  int row = lane & 7;
  int blk = ((kt << 2) + (lane >> 4)) ^ row;
  return *reinterpret_cast<const f16x8*>(lds + base + row * 64 + blk * 8);
}

__device__ __forceinline__ f16x8 mkfrag(const float* W, int row, int K, int kbase, int lane, bool ok) {
  f16x8 f;
  int k0 = kbase + ((lane >> 4) << 3);
#pragma unroll
  for (int j = 0; j < 8; ++j) {
    int k = k0 + j;
    float v = 0.0f;
    if (ok && k < K) v = W[row * K + k];
    f[j] = (_Float16)v;
  }
  return f;
}

__device__ __forceinline__ float rcpf(float x) { return __builtin_amdgcn_rcpf(x); }
__device__ __forceinline__ float ex2(float x)  { return __builtin_amdgcn_exp2f(x); }

__global__ __launch_bounds__(512, 2) void rnn_fused(
    const float* __restrict__ seq,
    const float* __restrict__ p1Wih, const float* __restrict__ p1Whh,
    const float* __restrict__ p1bih, const float* __restrict__ p1bhh,
    const float* __restrict__ p2Wih, const float* __restrict__ p2Whh,
    const float* __restrict__ p2bih, const float* __restrict__ p2bhh,
    const float* __restrict__ gW,    const float* __restrict__ gb,
    const float* __restrict__ rWih,  const float* __restrict__ rWhh,
    const float* __restrict__ rbih,  const float* __restrict__ rbhh,
    float* __restrict__ out)
{
  __shared__ __align__(16) _Float16 lds[LDS_N];
  const int tid  = threadIdx.x;
  const int lane = tid & 63;
  const int wv   = tid >> 6;
  const bool isR = (wv < 4);
  const int b0   = blockIdx.x * NROWS;
  const int ul   = lane & 15;
  const bool lo  = (lane < 32);
  const int grp4 = ((lane >> 4) & 1) * 4;
  const int row0 = grp4 + (lo ? 0 : 2);
  const float C1 = 1.44269504089f;

  for (int i = tid; i < LDS_N; i += 512) lds[i] = (_Float16)0.0f;

  // ---------------- r-wave state (GR staging + main GRU) ----------------
  f16x8 fghr[2], fghz[2], fghn[2], fgir[2], fgiz[2], fgin[2];
  float nbr2 = 0, nbz2 = 0, bin2 = 0, bhn2 = 0;
  float hq2[2] = {0, 0};
  int stA0 = 0, stA1 = 0, ldIdx = 0; bool stOK = false;
  int ahw2[2] = {0, 0};
  float* outp = nullptr;

  // ---------------- p-wave state (p-GRUs + gate + direct x) ----------------
  f16x8 pgi0[2], pgi1[2], pgi2[2], pgh0, pgh1, pgh2, fgw[2];
  float nbr = 0, nbz = 0, bin = 0, bhn = 0, gbias = 0;
  float h1q2[2] = {0, 0};
  int aphB = 0, up = 0; bool uok = false;
  int agw2[2] = {0, 0}, aphw2[2] = {0, 0}, arw2[2] = {0, 0};

  if (isR) {
    const int uR = wv * 16 + ul;
    fghr[0] = mkfrag(rWhh,       uR, 64,  0, lane, true);
    fghr[1] = mkfrag(rWhh,       uR, 64, 32, lane, true);
    fghz[0] = mkfrag(rWhh,  64 + uR, 64,  0, lane, true);
    fghz[1] = mkfrag(rWhh,  64 + uR, 64, 32, lane, true);
    fghn[0] = mkfrag(rWhh, 128 + uR, 64,  0, lane, true);
    fghn[1] = mkfrag(rWhh, 128 + uR, 64, 32, lane, true);
    fgir[0] = mkfrag(rWih,       uR, 42,  0, lane, true);
    fgir[1] = mkfrag(rWih,       uR, 42, 32, lane, true);
    fgiz[0] = mkfrag(rWih,  64 + uR, 42,  0, lane, true);
    fgiz[1] = mkfrag(rWih,  64 + uR, 42, 32, lane, true);
    fgin[0] = mkfrag(rWih, 128 + uR, 42,  0, lane, true);
    fgin[1] = mkfrag(rWih, 128 + uR, 42, 32, lane, true);
    nbr2 = -C1 * (rbih[uR] + rbhh[uR]);
    nbz2 = -C1 * (rbih[64 + uR] + rbhh[64 + uR]);
    bin2 = rbih[128 + uR]; bhn2 = rbhh[128 + uR];
    ahw2[0] = AH + swz(row0, uR);
    ahw2[1] = AH + swz(row0 + 1, uR);
    // GR staging map: 136 f32x2 items (xg/xr) over 256 r-threads, 1 slot
    {
      int ii = wv * 64 + lane;
      stOK = (ii < NGR);
      int iic = stOK ? ii : (NGR - 1);
      int rr = iic / 17, c2 = 49 + iic % 17;
      ldIdx = rr * 66 + c2;
      int a[2];
#pragma unroll
      for (int e = 0; e < 2; ++e) {
        int c = c2 * 2 + e;   // 98..131
        int tb, col;
        if (c < 106) { tb = AG; col = 40 + (c - 98); }
        else         { tb = AR; col = 16 + (c - 106); }
        a[e] = tb + swz(rr, col);
      }
      stA0 = a[0]; stA1 = a[1];
    }
    outp = out + (size_t)(b0 + row0) * 64 + uR;
  } else {
    const int pw  = wv - 4;
    const int gru = pw >> 1;
    const int s   = pw & 1;
    const float* Wih = gru ? p2Wih : p1Wih;
    const float* Whh = gru ? p2Whh : p1Whh;
    const float* bih = gru ? p2bih : p1bih;
    const float* bhh = gru ? p2bhh : p1bhh;
    up  = s * 16 + ul;
    uok = (up < 20);
    pgi0[0] = mkfrag(Wih,      up, 49,  0, lane, uok);
    pgi0[1] = mkfrag(Wih,      up, 49, 32, lane, uok);
    pgh0    = mkfrag(Whh,      up, 20,  0, lane, uok);
    pgi1[0] = mkfrag(Wih, 20 + up, 49,  0, lane, uok);
    pgi1[1] = mkfrag(Wih, 20 + up, 49, 32, lane, uok);
    pgh1    = mkfrag(Whh, 20 + up, 20,  0, lane, uok);
    pgi2[0] = mkfrag(Wih, 40 + up, 49,  0, lane, uok);
    pgi2[1] = mkfrag(Wih, 40 + up, 49, 32, lane, uok);
    pgh2    = mkfrag(Whh, 40 + up, 20,  0, lane, uok);
    fgw[0]  = mkfrag(gW, ul, 48,  0, lane, true);
    fgw[1]  = mkfrag(gW, ul, 48, 32, lane, true);
    gbias = gb[ul];
    if (uok) {
      nbr = -C1 * (bih[up] + bhh[up]);
      nbz = -C1 * (bih[20 + up] + bhh[20 + up]);
      bin = bih[40 + up]; bhn = bhh[40 + up];
    }
    aphB = gru ? AP2H : AP1H;
    const int gcol = gru ? (20 + up) : up;
#pragma unroll
    for (int j = 0; j < 2; ++j) {
      agw2[j]  = AG + swz(row0 + j, gcol);
      aphw2[j] = aphB + swz(row0 + j, up);
      arw2[j]  = AR + swz(row0 + j, ul);
    }
  }

  __syncthreads();  // zeros visible

  // ---- r prologue: load x(0..3) GR item into 4 slots; stage x(0) -> slot 0 ----
  f32x2 rs0{}, rs1{}, rs2{}, rs3{};
  const f32x2* spR = nullptr;
  // ---- p prologue: direct-x slots A<-x(0), B<-x(1); xp -> x(2) ----
  f32x4 xsA[4], xsB[4];
  const float* xp = nullptr;
  if (isR) {
    const f32x2* sp = reinterpret_cast<const f32x2*>(seq) + (size_t)b0 * (D_IN / 2);
    rs0 = sp[ldIdx];
    rs1 = sp[(size_t)1 * STEP2 + ldIdx];
    rs2 = sp[(size_t)2 * STEP2 + ldIdx];
    rs3 = sp[(size_t)3 * STEP2 + ldIdx];
    if (stOK) {
      lds[stA0] = (_Float16)rs0[0];
      lds[stA1] = (_Float16)rs0[1];
    }
    spR = sp + (size_t)4 * STEP2;
  } else {
    const int gru = (wv - 4) >> 1;
    const float* xb = seq + ((size_t)(b0 + (lane & 7)) * D_IN + gru * 49 + ((lane >> 4) << 3));
    xsA[0] = *reinterpret_cast<const f32x4*>(xb + 0);
    xsA[1] = *reinterpret_cast<const f32x4*>(xb + 4);
    xsA[2] = *reinterpret_cast<const f32x4*>(xb + 32);
    xsA[3] = *reinterpret_cast<const f32x4*>(xb + 36);
    xsB[0] = *reinterpret_cast<const f32x4*>(xb + STEPF + 0);
    xsB[1] = *reinterpret_cast<const f32x4*>(xb + STEPF + 4);
    xsB[2] = *reinterpret_cast<const f32x4*>(xb + STEPF + 32);
    xsB[3] = *reinterpret_cast<const f32x4*>(xb + STEPF + 36);
    xp = xb + (size_t)2 * STEPF;
  }
  __syncthreads();

  const f32x4 Z = {0.0f, 0.0f, 0.0f, 0.0f};  // persistent zero C-in

  // ---- r-wave phase f: stage GR x(f+1), prefetch x(f+4), main(t=f-2) ----
  auto rPhase = [&](int offGR, int slotA, int ahR, int ahW,
                    bool doMain, bool doStage, f32x2& rsStage, f32x2& rsLoad,
                    bool advance) {
    rsLoad = spR[ldIdx];                 // prefetch x(min(f+4,511)); in-flight
    if (advance) spR += STEP2;
    if (doStage && stOK) {
      lds[offGR + stA0] = (_Float16)rsStage[0];
      lds[offGR + stA1] = (_Float16)rsStage[1];
    }
    if (doMain) {
      f16x8 r0  = ldsFrag(lds, AR + slotA, lane, 0);
      f16x8 r1  = ldsFrag(lds, AR + slotA, lane, 1);
      f16x8 h0  = ldsFrag(lds, AH + ahR, lane, 0);
      f16x8 h1f = ldsFrag(lds, AH + ahR, lane, 1);
      f32x4 cR  = MFMA16(h0, fghr[0], Z);
      f32x4 cZ  = MFMA16(h0, fghz[0], Z);
      f32x4 cHN = MFMA16(h0, fghn[0], Z);
      cR  = MFMA16(h1f, fghr[1], cR);
      cZ  = MFMA16(h1f, fghz[1], cZ);
      cHN = MFMA16(h1f, fghn[1], cHN);
      cR  = MFMA16(r0, fgir[0], cR);  cR  = MFMA16(r1, fgir[1], cR);
      cZ  = MFMA16(r0, fgiz[0], cZ);  cZ  = MFMA16(r1, fgiz[1], cZ);
      f32x4 cIN = MFMA16(r0, fgin[0], Z);
      cIN = MFMA16(r1, fgin[1], cIN);
      float xRv[2] = { lo ? cR[0]  : cR[2],  lo ? cR[1]  : cR[3]  };
      float xZv[2] = { lo ? cZ[0]  : cZ[2],  lo ? cZ[1]  : cZ[3]  };
      float xHv[2] = { lo ? cHN[0] : cHN[2], lo ? cHN[1] : cHN[3] };
      float xIv[2] = { lo ? cIN[0] : cIN[2], lo ? cIN[1] : cIN[3] };
#pragma unroll
      for (int j = 0; j < 2; ++j) {
        float r   = rcpf(1.0f + ex2(fmaf(xRv[j], -C1, nbr2)));
        float z   = rcpf(1.0f + ex2(fmaf(xZv[j], -C1, nbz2)));
        float pre = fmaf(r, xHv[j] + bhn2, xIv[j] + bin2);
        float e2  = ex2(pre * (2.0f * C1));
        float n   = 1.0f - 2.0f * rcpf(1.0f + e2);
        float hv  = fmaf(z, hq2[j] - n, n);
        hq2[j] = hv;
        outp[j * 64] = hv;
        lds[ahW + ahw2[j]] = (_Float16)hv;
      }
      outp += (size_t)B_BATCH * 64;
    }
  };

  // ---- p-wave phase f: p-GRUs(t=f) from direct-x regs + gate(t=f-1) ----
  auto pPhase = [&](int pj, int agWr, int aphWr, int gSlot, bool doComp, bool doGate,
                    f32x4 (&xs)[4], bool advX) {
    if (doComp) {
      f16x8 a0, a1;
#pragma unroll
      for (int j = 0; j < 4; ++j) {
        a0[j]     = (_Float16)xs[0][j];
        a0[4 + j] = (_Float16)xs[1][j];
        a1[j]     = (_Float16)xs[2][j];
        a1[4 + j] = (_Float16)xs[3][j];
      }
      // issue next loads (x(f+2)) into the same slot; anti-dep after cvt
      xs[0] = *reinterpret_cast<const f32x4*>(xp + 0);
      xs[1] = *reinterpret_cast<const f32x4*>(xp + 4);
      xs[2] = *reinterpret_cast<const f32x4*>(xp + 32);
      xs[3] = *reinterpret_cast<const f32x4*>(xp + 36);
      if (advX) xp += STEPF;
      f16x8 ah = ldsFrag(lds, aphB + pj, lane, 0);
      f32x4 aR  = MFMA16(a0, pgi0[0], Z);
      f32x4 aZ  = MFMA16(a0, pgi1[0], Z);
      f32x4 aIN = MFMA16(a0, pgi2[0], Z);
      f32x4 aHN = MFMA16(ah, pgh2, Z);
      aR  = MFMA16(a1, pgi0[1], aR);  aR = MFMA16(ah, pgh0, aR);
      aZ  = MFMA16(a1, pgi1[1], aZ);  aZ = MFMA16(ah, pgh1, aZ);
      aIN = MFMA16(a1, pgi2[1], aIN);
      float xRv[2] = { lo ? aR[0]  : aR[2],  lo ? aR[1]  : aR[3]  };
      float xZv[2] = { lo ? aZ[0]  : aZ[2],  lo ? aZ[1]  : aZ[3]  };
      float xIv[2] = { lo ? aIN[0] : aIN[2], lo ? aIN[1] : aIN[3] };
      float xHv[2] = { lo ? aHN[0] : aHN[2], lo ? aHN[1] : aHN[3] };
#pragma unroll
      for (int j = 0; j < 2; ++j) {
        float r   = rcpf(1.0f + ex2(fmaf(xRv[j], -C1, nbr)));
        float z   = rcpf(1.0f + ex2(fmaf(xZv[j], -C1, nbz)));
        float pre = fmaf(r, xHv[j] + bhn, xIv[j] + bin);
        float e2  = ex2(pre * (2.0f * C1));
        float n   = 1.0f - 2.0f * rcpf(1.0f + e2);
        float hv  = fmaf(z, h1q2[j] - n, n);
        h1q2[j] = hv;
        if (uok) {
          _Float16 hh = (_Float16)hv;
          lds[agWr + agw2[j]]  = hh;   // -> AG slot f&3 (gate input, read @f+1)
          lds[aphWr + aphw2[j]] = hh;  // -> own h-path, read @f+1
        }
      }
    }
    if (doGate) {
      f16x8 g0 = ldsFrag(lds, AG + gSlot, lane, 0);
      f16x8 g1 = ldsFrag(lds, AG + gSlot, lane, 1);
      f32x4 cG = MFMA16(g0, fgw[0], Z);
      cG = MFMA16(g1, fgw[1], cG);
      float gv0 = lo ? cG[0] : cG[2], gv1 = lo ? cG[1] : cG[3];
      lds[gSlot + arw2[0]] = (_Float16)fmaxf(gv0 + gbias, 0.0f);  // AR slot (f-1)&3
      lds[gSlot + arw2[1]] = (_Float16)fmaxf(gv1 + gbias, 0.0f);
    }
  };

  // ---- main loop: f = 4i+j, i in [0,127], j in [0,3] ----
  for (int i = 0; i < T_STEPS / 4; ++i) {
    const bool i0 = (i == 0);
    const int f0 = 4 * i;
    // j=0: offGR=PX slotA=2PX ahR=PX ahW=0 | p: pj=0 agWr=0 aphWr=PX gSlot=3PX, xsA
    if (isR) rPhase(PX, 2 * PX, PX, 0, !i0, true, rs1, rs0, (f0 + 5 < T_STEPS));
    else     pPhase(0, 0, PX, 3 * PX, true, !i0, xsA, (f0 + 3 < T_STEPS));
    BARRIER();
    // j=1: offGR=2PX slotA=3PX ahR=0 ahW=PX | p: pj=PX agWr=PX aphWr=0 gSlot=0, xsB
    if (isR) rPhase(2 * PX, 3 * PX, 0, PX, !i0, true, rs2, rs1, (f0 + 6 < T_STEPS));
    else     pPhase(PX, PX, 0, 0, true, true, xsB, (f0 + 4 < T_STEPS));
    BARRIER();
    // j=2: offGR=3PX slotA=0 ahR=PX ahW=0 | p: pj=0 agWr=2PX aphWr=PX gSlot=PX, xsA
    if (isR) rPhase(3 * PX, 0, PX, 0, true, true, rs3, rs2, (f0 + 7 < T_STEPS));
    else     pPhase(0, 2 * PX, PX, PX, true, true, xsA, (f0 + 5 < T_STEPS));
    BARRIER();
    // j=3: offGR=0 slotA=PX ahR=0 ahW=PX | p: pj=PX agWr=3PX aphWr=0 gSlot=2PX, xsB
    if (isR) rPhase(0, PX, 0, PX, true, (i != T_STEPS / 4 - 1), rs0, rs3,
                    (f0 + 8 < T_STEPS));
    else     pPhase(PX, 3 * PX, 0, 2 * PX, true, true, xsB, (f0 + 6 < T_STEPS));
    BARRIER();
  }
  // ---- epilogue: f=512 (even): main(510) slotA=2PX ahR=PX ahW=0; p: gate(511) ----
  if (isR) rPhase(0, 2 * PX, PX, 0, true, false, rs0, rs1, false);
  else     pPhase(0, 0, PX, 3 * PX, false, true, xsA, false);
  BARRIER();
  // ---- f=513 (odd): main(511) slotA=3PX ahR=0 ahW=PX ----
  if (isR) rPhase(0, 3 * PX, 0, PX, true, false, rs0, rs1, false);
}

extern "C" void kernel_launch(void* const* d_in, const int* in_sizes, int n_in,
                              void* d_out, int out_size, void* d_ws, size_t ws_size,
                              hipStream_t stream) {
  (void)in_sizes; (void)n_in; (void)d_ws; (void)ws_size; (void)out_size;
  const float* seq   = (const float*)d_in[0];
  const float* p1Wih = (const float*)d_in[1];
  const float* p1Whh = (const float*)d_in[2];
  const float* p1bih = (const float*)d_in[3];
  const float* p1bhh = (const float*)d_in[4];
  const float* p2Wih = (const float*)d_in[5];
  const float* p2Whh = (const float*)d_in[6];
  const float* p2bih = (const float*)d_in[7];
  const float* p2bhh = (const float*)d_in[8];
  const float* gW    = (const float*)d_in[9];
  const float* gb    = (const float*)d_in[10];
  const float* rWih  = (const float*)d_in[11];
  const float* rWhh  = (const float*)d_in[12];
  const float* rbih  = (const float*)d_in[13];
  const float* rbhh  = (const float*)d_in[14];
  float* out = (float*)d_out;
  hipLaunchKernelGGL(rnn_fused, dim3(NBLOCKS), dim3(512), 0, stream,
                     seq, p1Wih, p1Whh, p1bih, p1bhh,
                     p2Wih, p2Whh, p2bih, p2bhh,
                     gW, gb, rWih, rWhh, rbih, rbhh, out);
}

// Round 15
// 302.151 us; speedup vs baseline: 5.8426x; 1.1661x over previous
//
#include <hip/hip_runtime.h>

// Fused persistent stacked-GRU kernel for MI355X (gfx950).
// Round-15: R12 (best, 305us) + DS-READ HOISTING: all ds_read_b128 issue at
// the top of each phase, before staging ds_writes/cvts (same-array LDS ops
// keep program order -- reads were stuck behind 6 writes on the dependent
// path). Otherwise identical to R12: 3-stage pipeline p||gate||main, gate on
// p-waves, mirrored A-rows (row=lane&7), persistent zero C-in, 1 lean
// barrier/phase, 4-step register prefetch of x on r-waves.
// 256 blocks x 8 rows, launch_bounds(512,2) (the only no-spill config).

#define T_STEPS 512
#define B_BATCH 2048
#define D_IN    132
#define NROWS   8
#define NBLOCKS 256
#define STEP2   (B_BATCH * D_IN / 2)   // f32x2 per timestep
#define NITEMS  (NROWS * 66)           // 528 f32x2 per step per block

typedef _Float16 f16x8 __attribute__((ext_vector_type(8)));
typedef float    f32x4 __attribute__((ext_vector_type(4)));
typedef float    f32x2 __attribute__((ext_vector_type(2)));

#define MFMA16(a, b, c) __builtin_amdgcn_mfma_f32_16x16x32_f16((a), (b), (c), 0, 0, 0)

// LDS tiles [16 rows][64 cols] fp16 = 1024 elems each; PX = slot stride.
#define PX    1024
#define AP1   0      // x_p1 cols 0..48                  (2 slots)
#define AP2   2048   // x_p2 cols 0..48                  (2 slots)
#define AG    4096   // h1:0-19 h2:20-39 xg:40-47        (4 slots)
#define AR    8192   // gate:0-15 xr:16-41               (4 slots)
#define AP1H  12288  // h1 cols 0..19                    (2 slots)
#define AP2H  14336  // h2 cols 0..19                    (2 slots)
#define AH    16384  // h cols 0..63                     (2 slots)
#define LDS_N 18432

// Raw barrier: LDS visibility only (lgkmcnt), NO vmcnt drain -> HBM prefetch
// stays in flight across barriers. seq read-only, out write-only.
#define BARRIER() do { \
    asm volatile("s_waitcnt lgkmcnt(0)\n\ts_barrier" ::: "memory"); \
    __builtin_amdgcn_sched_barrier(0); \
  } while (0)

__device__ __forceinline__ int swz(int row, int col) {
  return row * 64 + (((col >> 3) ^ (row & 7)) << 3) + (col & 7);
}

// A-fragment read with MIRRORED rows: row = lane&7 (rows 8-15 duplicate 0-7).
__device__ __forceinline__ f16x8 ldsFrag(const _Float16* lds, int base, int lane, int kt) {
  int row = lane & 7;
  int blk = ((kt << 2) + (lane >> 4)) ^ row;
  return *reinterpret_cast<const f16x8*>(lds + base + row * 64 + blk * 8);
}

__device__ __forceinline__ f16x8 mkfrag(const float* W, int row, int K, int kbase, int lane, bool ok) {
  f16x8 f;
  int k0 = kbase + ((lane >> 4) << 3);
#pragma unroll
  for (int j = 0; j < 8; ++j) {
    int k = k0 + j;
    float v = 0.0f;
    if (ok && k < K) v = W[row * K + k];
    f[j] = (_Float16)v;
  }
  return f;
}

__device__ __forceinline__ float rcpf(float x) { return __builtin_amdgcn_rcpf(x); }
__device__ __forceinline__ float ex2(float x)  { return __builtin_amdgcn_exp2f(x); }

__global__ __launch_bounds__(512, 2) void rnn_fused(
    const float* __restrict__ seq,
    const float* __restrict__ p1Wih, const float* __restrict__ p1Whh,
    const float* __restrict__ p1bih, const float* __restrict__ p1bhh,
    const float* __restrict__ p2Wih, const float* __restrict__ p2Whh,
    const float* __restrict__ p2bih, const float* __restrict__ p2bhh,
    const float* __restrict__ gW,    const float* __restrict__ gb,
    const float* __restrict__ rWih,  const float* __restrict__ rWhh,
    const float* __restrict__ rbih,  const float* __restrict__ rbhh,
    float* __restrict__ out)
{
  __shared__ __align__(16) _Float16 lds[LDS_N];
  const int tid  = threadIdx.x;
  const int lane = tid & 63;
  const int wv   = tid >> 6;
  const bool isR = (wv < 4);
  const int b0   = blockIdx.x * NROWS;
  const int ul   = lane & 15;
  const bool lo  = (lane < 32);
  const int grp4 = ((lane >> 4) & 1) * 4;
  const int row0 = grp4 + (lo ? 0 : 2);
  const float C1 = 1.44269504089f;

  for (int i = tid; i < LDS_N; i += 512) lds[i] = (_Float16)0.0f;

  // ---------------- r-wave state (staging + main GRU) ----------------
  f16x8 fghr[2], fghz[2], fghn[2], fgir[2], fgiz[2], fgin[2];
  float nbr2 = 0, nbz2 = 0, bin2 = 0, bhn2 = 0;
  float hq2[2] = {0, 0};
  int stAddr[3][2]; int ldIdx[3] = {0, 0, 0};
  bool stOK[3] = {false, false, false}, isP[3] = {false, false, false};
  int ahw2[2] = {0, 0};
  float* outp = nullptr;

  // ---------------- p-wave state (p-GRUs + gate) ----------------
  f16x8 pgi0[2], pgi1[2], pgi2[2], pgh0, pgh1, pgh2, fgw[2];
  float nbr = 0, nbz = 0, bin = 0, bhn = 0, gbias = 0;
  float h1q2[2] = {0, 0};
  int apB = 0, aphB = 0, up = 0; bool uok = false;
  int agw2[2] = {0, 0}, aphw2[2] = {0, 0}, arw2[2] = {0, 0};

  if (isR) {
    const int uR = wv * 16 + ul;
    fghr[0] = mkfrag(rWhh,       uR, 64,  0, lane, true);
    fghr[1] = mkfrag(rWhh,       uR, 64, 32, lane, true);
    fghz[0] = mkfrag(rWhh,  64 + uR, 64,  0, lane, true);
    fghz[1] = mkfrag(rWhh,  64 + uR, 64, 32, lane, true);
    fghn[0] = mkfrag(rWhh, 128 + uR, 64,  0, lane, true);
    fghn[1] = mkfrag(rWhh, 128 + uR, 64, 32, lane, true);
    fgir[0] = mkfrag(rWih,       uR, 42,  0, lane, true);
    fgir[1] = mkfrag(rWih,       uR, 42, 32, lane, true);
    fgiz[0] = mkfrag(rWih,  64 + uR, 42,  0, lane, true);
    fgiz[1] = mkfrag(rWih,  64 + uR, 42, 32, lane, true);
    fgin[0] = mkfrag(rWih, 128 + uR, 42,  0, lane, true);
    fgin[1] = mkfrag(rWih, 128 + uR, 42, 32, lane, true);
    nbr2 = -C1 * (rbih[uR] + rbhh[uR]);
    nbz2 = -C1 * (rbih[64 + uR] + rbhh[64 + uR]);
    bin2 = rbih[128 + uR]; bhn2 = rbhh[128 + uR];
    ahw2[0] = AH + swz(row0, uR);
    ahw2[1] = AH + swz(row0 + 1, uR);
    // staging map: 528 f32x2 items over 256 r-threads, 3 item-slots
#pragma unroll
    for (int it = 0; it < 3; ++it) {
      int ii = it * 256 + (wv * 64 + lane);
      stOK[it] = (ii < NITEMS);
      int iic = stOK[it] ? ii : (NITEMS - 1);
      ldIdx[it] = iic;
      int rr = iic / 66, c2 = iic % 66;
      isP[it] = (c2 < 49);
#pragma unroll
      for (int e = 0; e < 2; ++e) {
        int c = c2 * 2 + e;
        int tb, col;
        if (c < 49)       { tb = AP1; col = c; }
        else if (c < 98)  { tb = AP2; col = c - 49; }
        else if (c < 106) { tb = AG;  col = 40 + (c - 98); }
        else              { tb = AR;  col = 16 + (c - 106); }
        stAddr[it][e] = tb + swz(rr, col);
      }
    }
    outp = out + (size_t)(b0 + row0) * 64 + uR;
  } else {
    const int pw  = wv - 4;
    const int gru = pw >> 1;
    const int s   = pw & 1;
    const float* Wih = gru ? p2Wih : p1Wih;
    const float* Whh = gru ? p2Whh : p1Whh;
    const float* bih = gru ? p2bih : p1bih;
    const float* bhh = gru ? p2bhh : p1bhh;
    up  = s * 16 + ul;
    uok = (up < 20);
    pgi0[0] = mkfrag(Wih,      up, 49,  0, lane, uok);
    pgi0[1] = mkfrag(Wih,      up, 49, 32, lane, uok);
    pgh0    = mkfrag(Whh,      up, 20,  0, lane, uok);
    pgi1[0] = mkfrag(Wih, 20 + up, 49,  0, lane, uok);
    pgi1[1] = mkfrag(Wih, 20 + up, 49, 32, lane, uok);
    pgh1    = mkfrag(Whh, 20 + up, 20,  0, lane, uok);
    pgi2[0] = mkfrag(Wih, 40 + up, 49,  0, lane, uok);
    pgi2[1] = mkfrag(Wih, 40 + up, 49, 32, lane, uok);
    pgh2    = mkfrag(Whh, 40 + up, 20,  0, lane, uok);
    fgw[0]  = mkfrag(gW, ul, 48,  0, lane, true);
    fgw[1]  = mkfrag(gW, ul, 48, 32, lane, true);
    gbias = gb[ul];
    if (uok) {
      nbr = -C1 * (bih[up] + bhh[up]);
      nbz = -C1 * (bih[20 + up] + bhh[20 + up]);
      bin = bih[40 + up]; bhn = bhh[40 + up];
    }
    apB  = gru ? AP2  : AP1;
    aphB = gru ? AP2H : AP1H;
    const int gcol = gru ? (20 + up) : up;
#pragma unroll
    for (int j = 0; j < 2; ++j) {
      agw2[j]  = AG + swz(row0 + j, gcol);
      aphw2[j] = aphB + swz(row0 + j, up);
      arw2[j]  = AR + swz(row0 + j, ul);
    }
  }

  __syncthreads();  // zeros visible

  // ---- prologue (r-waves): load x(0..3) into 4 slots; stage x(0) -> slot 0 ----
  f32x2 rs0[3], rs1[3], rs2[3], rs3[3];
  const f32x2* spR = nullptr;
  if (isR) {
    const f32x2* sp = reinterpret_cast<const f32x2*>(seq) + (size_t)b0 * (D_IN / 2);
#pragma unroll
    for (int it = 0; it < 3; ++it) {
      rs0[it] = sp[ldIdx[it]];
      rs1[it] = sp[(size_t)1 * STEP2 + ldIdx[it]];
      rs2[it] = sp[(size_t)2 * STEP2 + ldIdx[it]];
      rs3[it] = sp[(size_t)3 * STEP2 + ldIdx[it]];
    }
#pragma unroll
    for (int it = 0; it < 3; ++it) if (stOK[it]) {
      lds[stAddr[it][0]] = (_Float16)rs0[it][0];   // all classes -> slot 0
      lds[stAddr[it][1]] = (_Float16)rs0[it][1];
    }
    spR = sp + (size_t)4 * STEP2;
  }
  __syncthreads();

  const f32x4 Z = {0.0f, 0.0f, 0.0f, 0.0f};  // persistent zero C-in

  // ---- r-wave phase f: [reads first] main(t=f-2); stage x(f+1); prefetch ----
  auto rPhase = [&](int offP, int offGR, int slotA, int ahR, int ahW,
                    bool doMain, bool doStage, f32x2 (&rsStage)[3], f32x2 (&rsLoad)[3],
                    bool advance) {
    // 1) critical ds_reads FIRST (they gate the MFMA+act chain)
    f16x8 r0, r1, h0, h1f;
    if (doMain) {
      r0  = ldsFrag(lds, AR + slotA, lane, 0);
      r1  = ldsFrag(lds, AR + slotA, lane, 1);
      h0  = ldsFrag(lds, AH + ahR, lane, 0);
      h1f = ldsFrag(lds, AH + ahR, lane, 1);
    }
    // 2) prefetch x(min(f+4,511)); stays in flight past barriers
#pragma unroll
    for (int it = 0; it < 3; ++it) rsLoad[it] = spR[ldIdx[it]];
    if (advance) spR += STEP2;
    // 3) staging writes (not on the dependent path)
    if (doStage) {
#pragma unroll
      for (int it = 0; it < 3; ++it) if (stOK[it]) {
        const int off = isP[it] ? offP : offGR;
        lds[off + stAddr[it][0]] = (_Float16)rsStage[it][0];
        lds[off + stAddr[it][1]] = (_Float16)rsStage[it][1];
      }
    }
    // 4) compute
    if (doMain) {
      f32x4 cR  = MFMA16(h0, fghr[0], Z);
      f32x4 cZ  = MFMA16(h0, fghz[0], Z);
      f32x4 cHN = MFMA16(h0, fghn[0], Z);
      cR  = MFMA16(h1f, fghr[1], cR);
      cZ  = MFMA16(h1f, fghz[1], cZ);
      cHN = MFMA16(h1f, fghn[1], cHN);
      cR  = MFMA16(r0, fgir[0], cR);  cR  = MFMA16(r1, fgir[1], cR);
      cZ  = MFMA16(r0, fgiz[0], cZ);  cZ  = MFMA16(r1, fgiz[1], cZ);
      f32x4 cIN = MFMA16(r0, fgin[0], Z);
      cIN = MFMA16(r1, fgin[1], cIN);
      // upper lanes use their OWN q=2,3 (valid: mirrored A-rows)
      float xRv[2] = { lo ? cR[0]  : cR[2],  lo ? cR[1]  : cR[3]  };
      float xZv[2] = { lo ? cZ[0]  : cZ[2],  lo ? cZ[1]  : cZ[3]  };
      float xHv[2] = { lo ? cHN[0] : cHN[2], lo ? cHN[1] : cHN[3] };
      float xIv[2] = { lo ? cIN[0] : cIN[2], lo ? cIN[1] : cIN[3] };
#pragma unroll
      for (int j = 0; j < 2; ++j) {
        float r   = rcpf(1.0f + ex2(fmaf(xRv[j], -C1, nbr2)));
        float z   = rcpf(1.0f + ex2(fmaf(xZv[j], -C1, nbz2)));
        float pre = fmaf(r, xHv[j] + bhn2, xIv[j] + bin2);
        float e2  = ex2(pre * (2.0f * C1));
        float n   = 1.0f - 2.0f * rcpf(1.0f + e2);
        float hv  = fmaf(z, hq2[j] - n, n);
        hq2[j] = hv;
        outp[j * 64] = hv;
        lds[ahW + ahw2[j]] = (_Float16)hv;
      }
      outp += (size_t)B_BATCH * 64;
    }
  };

  // ---- p-wave phase f: [reads first] p-GRUs(t=f) + gate(t=f-1) ----
  auto pPhase = [&](int pj, int agWr, int aphWr, int gSlot, bool doComp, bool doGate) {
    // 1) all ds_reads first
    f16x8 a0, a1, ah, g0, g1;
    if (doComp) {
      a0 = ldsFrag(lds, apB + pj, lane, 0);
      a1 = ldsFrag(lds, apB + pj, lane, 1);
      ah = ldsFrag(lds, aphB + pj, lane, 0);
    }
    if (doGate) {
      g0 = ldsFrag(lds, AG + gSlot, lane, 0);
      g1 = ldsFrag(lds, AG + gSlot, lane, 1);
    }
    // 2) compute
    if (doComp) {
      f32x4 aR  = MFMA16(a0, pgi0[0], Z);
      f32x4 aZ  = MFMA16(a0, pgi1[0], Z);
      f32x4 aIN = MFMA16(a0, pgi2[0], Z);
      f32x4 aHN = MFMA16(ah, pgh2, Z);
      aR  = MFMA16(a1, pgi0[1], aR);  aR = MFMA16(ah, pgh0, aR);
      aZ  = MFMA16(a1, pgi1[1], aZ);  aZ = MFMA16(ah, pgh1, aZ);
      aIN = MFMA16(a1, pgi2[1], aIN);
      float xRv[2] = { lo ? aR[0]  : aR[2],  lo ? aR[1]  : aR[3]  };
      float xZv[2] = { lo ? aZ[0]  : aZ[2],  lo ? aZ[1]  : aZ[3]  };
      float xIv[2] = { lo ? aIN[0] : aIN[2], lo ? aIN[1] : aIN[3] };
      float xHv[2] = { lo ? aHN[0] : aHN[2], lo ? aHN[1] : aHN[3] };
#pragma unroll
      for (int j = 0; j < 2; ++j) {
        float r   = rcpf(1.0f + ex2(fmaf(xRv[j], -C1, nbr)));
        float z   = rcpf(1.0f + ex2(fmaf(xZv[j], -C1, nbz)));
        float pre = fmaf(r, xHv[j] + bhn, xIv[j] + bin);
        float e2  = ex2(pre * (2.0f * C1));
        float n   = 1.0f - 2.0f * rcpf(1.0f + e2);
        float hv  = fmaf(z, h1q2[j] - n, n);
        h1q2[j] = hv;
        if (uok) {
          _Float16 hh = (_Float16)hv;
          lds[agWr + agw2[j]]  = hh;   // -> AG slot f&3 (gate input, read @f+1)
          lds[aphWr + aphw2[j]] = hh;  // -> own h-path, read @f+1
        }
      }
    }
    if (doGate) {
      f32x4 cG = MFMA16(g0, fgw[0], Z);
      cG = MFMA16(g1, fgw[1], cG);
      float gv0 = lo ? cG[0] : cG[2], gv1 = lo ? cG[1] : cG[3];
      lds[gSlot + arw2[0]] = (_Float16)fmaxf(gv0 + gbias, 0.0f);  // AR slot (f-1)&3
      lds[gSlot + arw2[1]] = (_Float16)fmaxf(gv1 + gbias, 0.0f);
    }
  };

  // ---- main loop: f = 4i+j, i in [0,127], j in [0,3] ----
  for (int i = 0; i < T_STEPS / 4; ++i) {
    const bool i0 = (i == 0);
    const int f0 = 4 * i;
    // j=0: offP=PX offGR=PX slotA=2PX ahR=PX ahW=0 | p: pj=0 agWr=0 aphWr=PX gSlot=3PX
    if (isR) rPhase(PX, PX, 2 * PX, PX, 0, !i0, true, rs1, rs0, (f0 + 5 < T_STEPS));
    else     pPhase(0, 0, PX, 3 * PX, true, !i0);
    BARRIER();
    // j=1: offP=0 offGR=2PX slotA=3PX ahR=0 ahW=PX | p: pj=PX agWr=PX aphWr=0 gSlot=0
    if (isR) rPhase(0, 2 * PX, 3 * PX, 0, PX, !i0, true, rs2, rs1, (f0 + 6 < T_STEPS));
    else     pPhase(PX, PX, 0, 0, true, true);
    BARRIER();
    // j=2: offP=PX offGR=3PX slotA=0 ahR=PX ahW=0 | p: pj=0 agWr=2PX aphWr=PX gSlot=PX
    if (isR) rPhase(PX, 3 * PX, 0, PX, 0, true, true, rs3, rs2, (f0 + 7 < T_STEPS));
    else     pPhase(0, 2 * PX, PX, PX, true, true);
    BARRIER();
    // j=3: offP=0 offGR=0 slotA=PX ahR=0 ahW=PX | p: pj=PX agWr=3PX aphWr=0 gSlot=2PX
    if (isR) rPhase(0, 0, PX, 0, PX, true, (i != T_STEPS / 4 - 1), rs0, rs3,
                    (f0 + 8 < T_STEPS));
    else     pPhase(PX, 3 * PX, 0, 2 * PX, true, true);
    BARRIER();
  }
  // ---- epilogue: f=512 (even): main(510) slotA=2PX ahR=PX ahW=0; p: gate(511) ----
  if (isR) rPhase(0, 0, 2 * PX, PX, 0, true, false, rs0, rs1, false);
  else     pPhase(0, 0, PX, 3 * PX, false, true);
  BARRIER();
  // ---- f=513 (odd): main(511) slotA=3PX ahR=0 ahW=PX ----
  if (isR) rPhase(0, 0, 3 * PX, 0, PX, true, false, rs0, rs1, false);
}

extern "C" void kernel_launch(void* const* d_in, const int* in_sizes, int n_in,
                              void* d_out, int out_size, void* d_ws, size_t ws_size,
                              hipStream_t stream) {
  (void)in_sizes; (void)n_in; (void)d_ws; (void)ws_size; (void)out_size;
  const float* seq   = (const float*)d_in[0];
  const float* p1Wih = (const float*)d_in[1];
  const float* p1Whh = (const float*)d_in[2];
  const float* p1bih = (const float*)d_in[3];
  const float* p1bhh = (const float*)d_in[4];
  const float* p2Wih = (const float*)d_in[5];
  const float* p2Whh = (const float*)d_in[6];
  const float* p2bih = (const float*)d_in[7];
  const float* p2bhh = (const float*)d_in[8];
  const float* gW    = (const float*)d_in[9];
  const float* gb    = (const float*)d_in[10];
  const float* rWih  = (const float*)d_in[11];
  const float* rWhh  = (const float*)d_in[12];
  const float* rbih  = (const float*)d_in[13];
  const float* rbhh  = (const float*)d_in[14];
  float* out = (float*)d_out;
  hipLaunchKernelGGL(rnn_fused, dim3(NBLOCKS), dim3(512), 0, stream,
                     seq, p1Wih, p1Whh, p1bih, p1bhh,
                     p2Wih, p2Whh, p2bih, p2bhh,
                     gW, gb, rWih, rWhh, rbih, rbhh, out);
}